// Round 5
// baseline (363.789 us; speedup 1.0000x reference)
//
#include <hip/hip_runtime.h>
#include <math.h>

#define N_VOX 200000
#define CCH   128
#define KOFF  27

typedef __attribute__((ext_vector_type(8))) short bf16x8;
typedef __attribute__((ext_vector_type(4))) float f32x4;

__device__ __forceinline__ float silu_f(float x) {
    return x / (1.0f + expf(-x));
}
__device__ __forceinline__ unsigned short f2bf(float x) {
    unsigned int u = __float_as_uint(x);
    u = (u + 0x7FFFu + ((u >> 16) & 1u)) >> 16;
    return (unsigned short)u;
}
// bijective XCD-aware block swizzle (m204 variant)
__device__ __forceinline__ int xcd_swz(int orig, int nwg) {
    int q = nwg >> 3, r = nwg & 7;
    int xcd = orig & 7, pos = orig >> 3;
    return (xcd < r ? xcd * (q + 1) : r * (q + 1) + (xcd - r) * q) + pos;
}

// ---------------------------------------------------------------------------
// Kernel 1: time embedding -> bf16 xeb[(N+1)][8] = {feat, sin*3, cos*3, 0}
// ---------------------------------------------------------------------------
__global__ void embed_kernel(const float* __restrict__ feat,
                             const int* __restrict__ t,
                             unsigned short* __restrict__ xeb) {
    int i = blockIdx.x * blockDim.x + threadIdx.x;
    if (i > N_VOX) return;
    union { unsigned short u[8]; int4 v; } o;
    if (i == N_VOX) {
        o.v = make_int4(0, 0, 0, 0);
    } else {
        o.u[0] = f2bf(feat[i]);
        float tf = (float)t[i];
#pragma unroll
        for (int kk = 0; kk < 3; ++kk) {
            float freq = (float)M_PI * (float)(1 << kk);
            float ang = tf * freq;
            o.u[1 + kk] = f2bf(sinf(ang));
            o.u[4 + kk] = f2bf(cosf(ang));
        }
        o.u[7] = 0;
    }
    *(int4*)(xeb + (size_t)i * 8) = o.v;
}

// ---------------------------------------------------------------------------
// Weight repacks to MFMA-fragment-linear bf16 (B-operand layout).
// ---------------------------------------------------------------------------
__global__ void convert_w1(const float* __restrict__ W1,
                           unsigned short* __restrict__ W1f) {
    int g = blockIdx.x * 256 + threadIdx.x;
    if (g >= 7 * 8 * 64) return;
    int l = g & 63;
    int rest = g >> 6;
    int nf = rest & 7;
    int kk = rest >> 3;
    int o = kk * 4 + (l >> 4);
    int co = nf * 16 + (l & 15);
    union { unsigned short u[8]; int4 v; } out;
#pragma unroll
    for (int j = 0; j < 8; ++j) {
        float w = 0.f;
        if (o < KOFF && j < 7) w = W1[((size_t)o * 7 + j) * CCH + co];
        out.u[j] = f2bf(w);
    }
    *(int4*)(W1f + (size_t)g * 8) = out.v;
}

__global__ void convert_w2(const float* __restrict__ W2,
                           unsigned short* __restrict__ W2f) {
    int g = blockIdx.x * 256 + threadIdx.x;
    int l = g & 63;
    int rest = g >> 6;
    int nf = rest & 7;
    int kkk = rest >> 3;
    int k = kkk >> 2, kk = kkk & 3;
    int ci0 = kk * 32 + (l >> 4) * 8;
    int co = nf * 16 + (l & 15);
    union { unsigned short u[8]; int4 v; } out;
#pragma unroll
    for (int j = 0; j < 8; ++j)
        out.u[j] = f2bf(W2[((size_t)k * CCH + ci0 + j) * CCH + co]);
    *(int4*)(W2f + (size_t)g * 8) = out.v;
}

__global__ void convert_w3(const float* __restrict__ W3,
                           unsigned short* __restrict__ W3f) {
    int g = blockIdx.x * 256 + threadIdx.x;
    if (g >= 4 * 8 * 64) return;
    int l = g & 63;
    int rest = g >> 6;
    int nf = rest & 7;
    int kk = rest >> 3;
    int ci0 = kk * 32 + (l >> 4) * 8;
    int co = nf * 16 + (l & 15);
    union { unsigned short u[8]; int4 v; } out;
#pragma unroll
    for (int j = 0; j < 8; ++j)
        out.u[j] = f2bf(W3[(size_t)(ci0 + j) * CCH + co]);
    *(int4*)(W3f + (size_t)g * 8) = out.v;
}

// ---------------------------------------------------------------------------
// Kernel 2: conv1 via MFMA. 128 vox x 128 ch per block, K = 7 steps of 32.
// ---------------------------------------------------------------------------
__global__ __launch_bounds__(256) void conv1_mfma(
    const unsigned short* __restrict__ xeb, const int* __restrict__ nidx,
    const unsigned short* __restrict__ W1f, const float* __restrict__ b1,
    unsigned short* __restrict__ h1b) {
    __shared__ int4 bufmem[2048];
    __shared__ int idxAll[128 * 28];

    int tid = threadIdx.x;
    int l = tid & 63, w = tid >> 6;
    int mw = w >> 1, nwv = w & 1;
    int wg = xcd_swz(blockIdx.x, gridDim.x);
    int v0 = wg * 128;

    for (int g = tid; g < KOFF * 128; g += 256) {
        int k = g >> 7, vi = g & 127;
        int v = v0 + vi;
        idxAll[vi * 28 + k] = (v < N_VOX) ? nidx[(size_t)k * N_VOX + v] : N_VOX;
    }
    if (tid < 128) idxAll[tid * 28 + 27] = N_VOX;
    __syncthreads();

    f32x4 acc[4][4];
#pragma unroll
    for (int m = 0; m < 4; ++m)
#pragma unroll
        for (int n = 0; n < 4; ++n) acc[m][n] = (f32x4)0.f;

    {
        int4 g0[2]; int rr[2], cc[2];
#pragma unroll
        for (int u = 0; u < 2; ++u) {
            int q = u * 256 + tid;
            int r = q >> 2, oo = q & 3;
            int idx = idxAll[r * 28 + oo];
            g0[u] = *(const int4*)(xeb + (size_t)idx * 8);
            rr[u] = r; cc[u] = oo ^ (r & 3);
        }
#pragma unroll
        for (int u = 0; u < 2; ++u) bufmem[rr[u] * 5 + cc[u]] = g0[u];
    }
    __syncthreads();

    for (int kk = 0; kk < 7; ++kk) {
        int cur = kk & 1;
        int4 gg[2]; int rr[2], cc[2];
        if (kk < 6) {
#pragma unroll
            for (int u = 0; u < 2; ++u) {
                int q = u * 256 + tid;
                int r = q >> 2, oo = q & 3;
                int idx = idxAll[r * 28 + (kk + 1) * 4 + oo];
                gg[u] = *(const int4*)(xeb + (size_t)idx * 8);
                rr[u] = r; cc[u] = oo ^ (r & 3);
            }
        }
        bf16x8 a[4], b[4];
#pragma unroll
        for (int n = 0; n < 4; ++n) {
            int nf = nwv * 4 + n;
            b[n] = *(const bf16x8*)(W1f + ((size_t)(kk * 8 + nf) * 64 + l) * 8);
        }
#pragma unroll
        for (int m = 0; m < 4; ++m) {
            int r = mw * 64 + m * 16 + (l & 15);
            int c = l >> 4;
            a[m] = *(const bf16x8*)&bufmem[cur * 640 + r * 5 + (c ^ (r & 3))];
        }
#pragma unroll
        for (int m = 0; m < 4; ++m)
#pragma unroll
            for (int n = 0; n < 4; ++n)
                acc[m][n] = __builtin_amdgcn_mfma_f32_16x16x32_bf16(
                    a[m], b[n], acc[m][n], 0, 0, 0);
        if (kk < 6) {
#pragma unroll
            for (int u = 0; u < 2; ++u)
                bufmem[(cur ^ 1) * 640 + rr[u] * 5 + cc[u]] = gg[u];
        }
        __syncthreads();
    }

    float bias[4];
#pragma unroll
    for (int n = 0; n < 4; ++n) bias[n] = b1[nwv * 64 + n * 16 + (l & 15)];
    unsigned short* H16 = (unsigned short*)bufmem;
#pragma unroll
    for (int m = 0; m < 4; ++m) {
        int rbase = mw * 64 + m * 16 + (l >> 4) * 4;
#pragma unroll
        for (int n = 0; n < 4; ++n) {
            int ch = nwv * 64 + n * 16 + (l & 15);
            int c = ch >> 3;
            f32x4 d = acc[m][n];
#pragma unroll
            for (int ri = 0; ri < 4; ++ri) {
                int r = rbase + ri;
                int s = (c & 8) | ((c & 7) ^ (r & 7));
                H16[r * 128 + s * 8 + (ch & 7)] = f2bf(silu_f(d[ri] + bias[n]));
            }
        }
    }
    __syncthreads();
#pragma unroll
    for (int u = 0; u < 8; ++u) {
        int q = u * 256 + tid;
        int r = q >> 4, s = q & 15;
        int c = (s & 8) | ((s & 7) ^ (r & 7));
        int v = v0 + r;
        if (v < N_VOX)
            *(int4*)(h1b + (size_t)v * CCH + c * 8) = bufmem[r * 16 + s];
    }
    if (blockIdx.x == 0 && tid < 16)
        *(int4*)(h1b + (size_t)N_VOX * CCH + tid * 8) = make_int4(0, 0, 0, 0);
}

// ---------------------------------------------------------------------------
// Kernel 3: conv2 via MFMA + fused tail. BARRIER-FREE main loop:
// per-lane direct global A-fragment loads (16B each; lanes {l,l+16,l+32,l+48}
// form 64B runs over the same voxel row), register-double-buffered one k
// ahead via manual 2x unroll. idx table in LDS (one barrier at start).
// ---------------------------------------------------------------------------
#define LOAD_A(dst, kq) {                                                  \
    int _i0 = idxp[(kq) * 64];                                             \
    int _i1 = idxp[(kq) * 64 + 16];                                        \
    int _o0 = (_i0 << 8) + lane_c16;                                       \
    int _o1 = (_i1 << 8) + lane_c16;                                       \
    const char* _h = (const char*)h1b;                                     \
    dst[0][0] = *(const bf16x8*)(_h + _o0);                                \
    dst[0][1] = *(const bf16x8*)(_h + _o0 + 64);                           \
    dst[0][2] = *(const bf16x8*)(_h + _o0 + 128);                          \
    dst[0][3] = *(const bf16x8*)(_h + _o0 + 192);                          \
    dst[1][0] = *(const bf16x8*)(_h + _o1);                                \
    dst[1][1] = *(const bf16x8*)(_h + _o1 + 64);                           \
    dst[1][2] = *(const bf16x8*)(_h + _o1 + 128);                         \
    dst[1][3] = *(const bf16x8*)(_h + _o1 + 192);                          \
}

#define BODY(KQ, AC, AN) {                                                 \
    const unsigned short* _wb = W2f + (size_t)(KQ) * 16384;                \
    bf16x8 _b0[4], _b1[4];                                                 \
    _Pragma("unroll") for (int n = 0; n < 4; ++n) {                        \
        int nf = nwv * 4 + n;                                              \
        _b0[n] = *(const bf16x8*)(_wb + ((0 * 8 + nf) * 64 + l) * 8);      \
        _b1[n] = *(const bf16x8*)(_wb + ((1 * 8 + nf) * 64 + l) * 8);      \
    }                                                                      \
    LOAD_A(AN, (KQ) + 1);                                                  \
    _Pragma("unroll") for (int n = 0; n < 4; ++n) {                        \
        acc[0][n] = __builtin_amdgcn_mfma_f32_16x16x32_bf16(AC[0][0], _b0[n], acc[0][n], 0, 0, 0); \
        acc[1][n] = __builtin_amdgcn_mfma_f32_16x16x32_bf16(AC[1][0], _b0[n], acc[1][n], 0, 0, 0); \
        acc[0][n] = __builtin_amdgcn_mfma_f32_16x16x32_bf16(AC[0][1], _b1[n], acc[0][n], 0, 0, 0); \
        acc[1][n] = __builtin_amdgcn_mfma_f32_16x16x32_bf16(AC[1][1], _b1[n], acc[1][n], 0, 0, 0); \
    }                                                                      \
    _Pragma("unroll") for (int n = 0; n < 4; ++n) {                        \
        int nf = nwv * 4 + n;                                              \
        _b0[n] = *(const bf16x8*)(_wb + ((2 * 8 + nf) * 64 + l) * 8);      \
        _b1[n] = *(const bf16x8*)(_wb + ((3 * 8 + nf) * 64 + l) * 8);      \
    }                                                                      \
    _Pragma("unroll") for (int n = 0; n < 4; ++n) {                        \
        acc[0][n] = __builtin_amdgcn_mfma_f32_16x16x32_bf16(AC[0][2], _b0[n], acc[0][n], 0, 0, 0); \
        acc[1][n] = __builtin_amdgcn_mfma_f32_16x16x32_bf16(AC[1][2], _b0[n], acc[1][n], 0, 0, 0); \
        acc[0][n] = __builtin_amdgcn_mfma_f32_16x16x32_bf16(AC[0][3], _b1[n], acc[0][n], 0, 0, 0); \
        acc[1][n] = __builtin_amdgcn_mfma_f32_16x16x32_bf16(AC[1][3], _b1[n], acc[1][n], 0, 0, 0); \
    }                                                                      \
}

__global__ __launch_bounds__(256, 3) void conv2_mfma(
    const unsigned short* __restrict__ h1b, const int* __restrict__ nidx,
    const unsigned short* __restrict__ W2f, const float* __restrict__ b2,
    const unsigned short* __restrict__ W3f, const float* __restrict__ b3,
    const float* __restrict__ W4, const float* __restrict__ b4,
    float* __restrict__ out) {
    __shared__ int idxAll[28 * 64];           // [k][vi]; reused as Osum in tail
    __shared__ unsigned short H16[64 * 128];  // 16 KB epilogue tile

    int tid = threadIdx.x;
    int l = tid & 63, w = tid >> 6;
    int mw = w >> 1, nwv = w & 1;
    int wg = xcd_swz(blockIdx.x, gridDim.x);
    int v0 = wg * 64;

    for (int g = tid; g < KOFF * 64; g += 256) {
        int k = g >> 6, vi = g & 63;
        int v = v0 + vi;
        idxAll[g] = (v < N_VOX) ? nidx[(size_t)k * N_VOX + v] : N_VOX;
    }
    if (tid < 64) idxAll[KOFF * 64 + tid] = N_VOX;  // pad row -> safe prefetch
    __syncthreads();

    f32x4 acc[2][4];
#pragma unroll
    for (int m = 0; m < 2; ++m)
#pragma unroll
        for (int n = 0; n < 4; ++n) acc[m][n] = (f32x4)0.f;

    // per-lane constants
    int vi0 = mw * 32 + (l & 15);        // m=0 row within block
    const int* idxp = &idxAll[vi0];      // idxp[k*64] (m=0), idxp[k*64+16] (m=1)
    int lane_c16 = (l >> 4) * 16;        // byte offset of this lane's 16B chunk

    bf16x8 aE[2][4], aO[2][4];
    LOAD_A(aE, 0);
    for (int k = 0; k < 26; k += 2) {
        BODY(k, aE, aO);
        BODY(k + 1, aO, aE);
    }
    BODY(26, aE, aO);   // prefetch of k=27 hits sentinel pad row (DCE-able)

    // ---- fused tail: H = bf16(silu(acc+b2)) -> LDS; P = H @ W3; out ----
    float bias2[4];
#pragma unroll
    for (int n = 0; n < 4; ++n) bias2[n] = b2[nwv * 64 + n * 16 + (l & 15)];
#pragma unroll
    for (int m = 0; m < 2; ++m) {
        int rbase = mw * 32 + m * 16 + (l >> 4) * 4;
#pragma unroll
        for (int n = 0; n < 4; ++n) {
            int ch = nwv * 64 + n * 16 + (l & 15);
            int c = ch >> 3;
            f32x4 d = acc[m][n];
#pragma unroll
            for (int ri = 0; ri < 4; ++ri) {
                int r = rbase + ri;
                int s = (c & 8) | ((c & 7) ^ (r & 7));
                H16[r * 128 + s * 8 + (ch & 7)] = f2bf(silu_f(d[ri] + bias2[n]));
            }
        }
    }
    __syncthreads();

    f32x4 p[2][4];
#pragma unroll
    for (int m = 0; m < 2; ++m)
#pragma unroll
        for (int n = 0; n < 4; ++n) p[m][n] = (f32x4)0.f;
#pragma unroll
    for (int kk = 0; kk < 4; ++kk) {
        bf16x8 a[2], b[4];
#pragma unroll
        for (int n = 0; n < 4; ++n) {
            int nf = nwv * 4 + n;
            b[n] = *(const bf16x8*)(W3f + ((size_t)(kk * 8 + nf) * 64 + l) * 8);
        }
#pragma unroll
        for (int m = 0; m < 2; ++m) {
            int r = mw * 32 + m * 16 + (l & 15);
            int c = kk * 4 + (l >> 4);
            int s = (c & 8) | ((c & 7) ^ (r & 7));
            a[m] = *(const bf16x8*)&H16[r * 128 + s * 8];
        }
#pragma unroll
        for (int m = 0; m < 2; ++m)
#pragma unroll
            for (int n = 0; n < 4; ++n)
                p[m][n] = __builtin_amdgcn_mfma_f32_16x16x32_bf16(
                    a[m], b[n], p[m][n], 0, 0, 0);
    }

    float w4v[4], b3v[4];
#pragma unroll
    for (int n = 0; n < 4; ++n) {
        int ch = nwv * 64 + n * 16 + (l & 15);
        w4v[n] = W4[ch];
        b3v[n] = b3[ch];
    }
    float* Osum = (float*)idxAll;
#pragma unroll
    for (int m = 0; m < 2; ++m) {
        float po[4] = {0.f, 0.f, 0.f, 0.f};
#pragma unroll
        for (int n = 0; n < 4; ++n) {
            f32x4 d = p[m][n];
#pragma unroll
            for (int ri = 0; ri < 4; ++ri)
                po[ri] += silu_f(d[ri] + b3v[n]) * w4v[n];
        }
#pragma unroll
        for (int off = 1; off < 16; off <<= 1)
#pragma unroll
            for (int ri = 0; ri < 4; ++ri)
                po[ri] += __shfl_xor(po[ri], off, 64);
        if ((l & 15) == 0) {
            int rbase = mw * 32 + m * 16 + (l >> 4) * 4;
#pragma unroll
            for (int ri = 0; ri < 4; ++ri)
                Osum[nwv * 64 + rbase + ri] = po[ri];
        }
    }
    __syncthreads();
    if (tid < 64) {
        int v = v0 + tid;
        if (v < N_VOX) out[v] = Osum[tid] + Osum[64 + tid] + b4[0];
    }
}

// ---------------------------------------------------------------------------
extern "C" void kernel_launch(void* const* d_in, const int* in_sizes, int n_in,
                              void* d_out, int out_size, void* d_ws,
                              size_t ws_size, hipStream_t stream) {
    const float* feat = (const float*)d_in[0];
    const int* t      = (const int*)d_in[1];
    const int* nidx   = (const int*)d_in[2];
    const float* W1   = (const float*)d_in[3];
    const float* b1   = (const float*)d_in[4];
    const float* W2   = (const float*)d_in[5];
    const float* b2   = (const float*)d_in[6];
    const float* W3   = (const float*)d_in[7];
    const float* b3   = (const float*)d_in[8];
    const float* W4   = (const float*)d_in[9];
    const float* b4   = (const float*)d_in[10];
    float* out = (float*)d_out;

    char* ws = (char*)d_ws;
    size_t off = 0;
    unsigned short* xeb = (unsigned short*)(ws + off);
    off += ((size_t)(N_VOX + 1) * 8 * 2 + 255) & ~(size_t)255;
    unsigned short* h1b = (unsigned short*)(ws + off);
    off += ((size_t)(N_VOX + 1) * CCH * 2 + 255) & ~(size_t)255;
    unsigned short* W1f = (unsigned short*)(ws + off);
    off += ((size_t)7 * 8 * 64 * 8 * 2 + 255) & ~(size_t)255;
    unsigned short* W2f = (unsigned short*)(ws + off);
    off += ((size_t)KOFF * 4 * 8 * 64 * 8 * 2 + 255) & ~(size_t)255;
    unsigned short* W3f = (unsigned short*)(ws + off);

    int grid1 = (N_VOX + 127) / 128;
    int grid2 = (N_VOX + 63) / 64;
    embed_kernel<<<(N_VOX + 1 + 255) / 256, 256, 0, stream>>>(feat, t, xeb);
    convert_w1<<<(7 * 8 * 64 + 255) / 256, 256, 0, stream>>>(W1, W1f);
    convert_w2<<<(KOFF * 4 * 8 * 64) / 256, 256, 0, stream>>>(W2, W2f);
    convert_w3<<<(4 * 8 * 64 + 255) / 256, 256, 0, stream>>>(W3, W3f);
    conv1_mfma<<<grid1, 256, 0, stream>>>(xeb, nidx, W1f, b1, h1b);
    conv2_mfma<<<grid2, 256, 0, stream>>>(h1b, nidx, W2f, b2, W3f, b3, W4, b4, out);
}

// Round 7
// 296.490 us; speedup vs baseline: 1.2270x; 1.2270x over previous
//
#include <hip/hip_runtime.h>
#include <math.h>

#define N_VOX 200000
#define CCH   128
#define KOFF  27

typedef __attribute__((ext_vector_type(8))) short bf16x8;
typedef __attribute__((ext_vector_type(4))) float f32x4;

__device__ __forceinline__ float silu_f(float x) {
    return x / (1.0f + expf(-x));
}
__device__ __forceinline__ unsigned short f2bf(float x) {
    unsigned int u = __float_as_uint(x);
    u = (u + 0x7FFFu + ((u >> 16) & 1u)) >> 16;
    return (unsigned short)u;
}
// bijective XCD-aware block swizzle (m204 variant)
__device__ __forceinline__ int xcd_swz(int orig, int nwg) {
    int q = nwg >> 3, r = nwg & 7;
    int xcd = orig & 7, pos = orig >> 3;
    return (xcd < r ? xcd * (q + 1) : r * (q + 1) + (xcd - r) * q) + pos;
}
// async 16B global -> LDS (direct-to-shared DMA)
__device__ __forceinline__ void gload_lds16(const void* g, void* l) {
    __builtin_amdgcn_global_load_lds(
        (const __attribute__((address_space(1))) unsigned int*)g,
        (__attribute__((address_space(3))) unsigned int*)l, 16, 0, 0);
}

// ---------------------------------------------------------------------------
// Kernel 1: time embedding -> bf16 xeb[(N+1)][8] = {feat, sin*3, cos*3, 0}
// ---------------------------------------------------------------------------
__global__ void embed_kernel(const float* __restrict__ feat,
                             const int* __restrict__ t,
                             unsigned short* __restrict__ xeb) {
    int i = blockIdx.x * blockDim.x + threadIdx.x;
    if (i > N_VOX) return;
    union { unsigned short u[8]; int4 v; } o;
    if (i == N_VOX) {
        o.v = make_int4(0, 0, 0, 0);
    } else {
        o.u[0] = f2bf(feat[i]);
        float tf = (float)t[i];
#pragma unroll
        for (int kk = 0; kk < 3; ++kk) {
            float freq = (float)M_PI * (float)(1 << kk);
            float ang = tf * freq;
            o.u[1 + kk] = f2bf(sinf(ang));
            o.u[4 + kk] = f2bf(cosf(ang));
        }
        o.u[7] = 0;
    }
    *(int4*)(xeb + (size_t)i * 8) = o.v;
}

// ---------------------------------------------------------------------------
// Weight repacks to MFMA-fragment-linear bf16 (B-operand layout).
// ---------------------------------------------------------------------------
__global__ void convert_w1(const float* __restrict__ W1,
                           unsigned short* __restrict__ W1f) {
    int g = blockIdx.x * 256 + threadIdx.x;
    if (g >= 7 * 8 * 64) return;
    int l = g & 63;
    int rest = g >> 6;
    int nf = rest & 7;
    int kk = rest >> 3;
    int o = kk * 4 + (l >> 4);
    int co = nf * 16 + (l & 15);
    union { unsigned short u[8]; int4 v; } out;
#pragma unroll
    for (int j = 0; j < 8; ++j) {
        float w = 0.f;
        if (o < KOFF && j < 7) w = W1[((size_t)o * 7 + j) * CCH + co];
        out.u[j] = f2bf(w);
    }
    *(int4*)(W1f + (size_t)g * 8) = out.v;
}

__global__ void convert_w2(const float* __restrict__ W2,
                           unsigned short* __restrict__ W2f) {
    int g = blockIdx.x * 256 + threadIdx.x;
    int l = g & 63;
    int rest = g >> 6;
    int nf = rest & 7;
    int kkk = rest >> 3;
    int k = kkk >> 2, kk = kkk & 3;
    int ci0 = kk * 32 + (l >> 4) * 8;
    int co = nf * 16 + (l & 15);
    union { unsigned short u[8]; int4 v; } out;
#pragma unroll
    for (int j = 0; j < 8; ++j)
        out.u[j] = f2bf(W2[((size_t)k * CCH + ci0 + j) * CCH + co]);
    *(int4*)(W2f + (size_t)g * 8) = out.v;
}

__global__ void convert_w3(const float* __restrict__ W3,
                           unsigned short* __restrict__ W3f) {
    int g = blockIdx.x * 256 + threadIdx.x;
    if (g >= 4 * 8 * 64) return;
    int l = g & 63;
    int rest = g >> 6;
    int nf = rest & 7;
    int kk = rest >> 3;
    int ci0 = kk * 32 + (l >> 4) * 8;
    int co = nf * 16 + (l & 15);
    union { unsigned short u[8]; int4 v; } out;
#pragma unroll
    for (int j = 0; j < 8; ++j)
        out.u[j] = f2bf(W3[(size_t)(ci0 + j) * CCH + co]);
    *(int4*)(W3f + (size_t)g * 8) = out.v;
}

// ---------------------------------------------------------------------------
// Kernel 2: conv1 via MFMA. 128 vox x 128 ch per block, K = 7 steps of 32.
// ---------------------------------------------------------------------------
__global__ __launch_bounds__(256) void conv1_mfma(
    const unsigned short* __restrict__ xeb, const int* __restrict__ nidx,
    const unsigned short* __restrict__ W1f, const float* __restrict__ b1,
    unsigned short* __restrict__ h1b) {
    __shared__ int4 bufmem[2048];
    __shared__ int idxAll[128 * 28];

    int tid = threadIdx.x;
    int l = tid & 63, w = tid >> 6;
    int mw = w >> 1, nwv = w & 1;
    int wg = xcd_swz(blockIdx.x, gridDim.x);
    int v0 = wg * 128;

    for (int g = tid; g < KOFF * 128; g += 256) {
        int k = g >> 7, vi = g & 127;
        int v = v0 + vi;
        idxAll[vi * 28 + k] = (v < N_VOX) ? nidx[(size_t)k * N_VOX + v] : N_VOX;
    }
    if (tid < 128) idxAll[tid * 28 + 27] = N_VOX;
    __syncthreads();

    f32x4 acc[4][4];
#pragma unroll
    for (int m = 0; m < 4; ++m)
#pragma unroll
        for (int n = 0; n < 4; ++n) acc[m][n] = (f32x4)0.f;

    {
        int4 g0[2]; int rr[2], cc[2];
#pragma unroll
        for (int u = 0; u < 2; ++u) {
            int q = u * 256 + tid;
            int r = q >> 2, oo = q & 3;
            int idx = idxAll[r * 28 + oo];
            g0[u] = *(const int4*)(xeb + (size_t)idx * 8);
            rr[u] = r; cc[u] = oo ^ (r & 3);
        }
#pragma unroll
        for (int u = 0; u < 2; ++u) bufmem[rr[u] * 5 + cc[u]] = g0[u];
    }
    __syncthreads();

    for (int kk = 0; kk < 7; ++kk) {
        int cur = kk & 1;
        int4 gg[2]; int rr[2], cc[2];
        if (kk < 6) {
#pragma unroll
            for (int u = 0; u < 2; ++u) {
                int q = u * 256 + tid;
                int r = q >> 2, oo = q & 3;
                int idx = idxAll[r * 28 + (kk + 1) * 4 + oo];
                gg[u] = *(const int4*)(xeb + (size_t)idx * 8);
                rr[u] = r; cc[u] = oo ^ (r & 3);
            }
        }
        bf16x8 a[4], b[4];
#pragma unroll
        for (int n = 0; n < 4; ++n) {
            int nf = nwv * 4 + n;
            b[n] = *(const bf16x8*)(W1f + ((size_t)(kk * 8 + nf) * 64 + l) * 8);
        }
#pragma unroll
        for (int m = 0; m < 4; ++m) {
            int r = mw * 64 + m * 16 + (l & 15);
            int c = l >> 4;
            a[m] = *(const bf16x8*)&bufmem[cur * 640 + r * 5 + (c ^ (r & 3))];
        }
#pragma unroll
        for (int m = 0; m < 4; ++m)
#pragma unroll
            for (int n = 0; n < 4; ++n)
                acc[m][n] = __builtin_amdgcn_mfma_f32_16x16x32_bf16(
                    a[m], b[n], acc[m][n], 0, 0, 0);
        if (kk < 6) {
#pragma unroll
            for (int u = 0; u < 2; ++u)
                bufmem[(cur ^ 1) * 640 + rr[u] * 5 + cc[u]] = gg[u];
        }
        __syncthreads();
    }

    float bias[4];
#pragma unroll
    for (int n = 0; n < 4; ++n) bias[n] = b1[nwv * 64 + n * 16 + (l & 15)];
    unsigned short* H16 = (unsigned short*)bufmem;
#pragma unroll
    for (int m = 0; m < 4; ++m) {
        int rbase = mw * 64 + m * 16 + (l >> 4) * 4;
#pragma unroll
        for (int n = 0; n < 4; ++n) {
            int ch = nwv * 64 + n * 16 + (l & 15);
            int c = ch >> 3;
            f32x4 d = acc[m][n];
#pragma unroll
            for (int ri = 0; ri < 4; ++ri) {
                int r = rbase + ri;
                int s = (c & 8) | ((c & 7) ^ (r & 7));
                H16[r * 128 + s * 8 + (ch & 7)] = f2bf(silu_f(d[ri] + bias[n]));
            }
        }
    }
    __syncthreads();
#pragma unroll
    for (int u = 0; u < 8; ++u) {
        int q = u * 256 + tid;
        int r = q >> 4, s = q & 15;
        int c = (s & 8) | ((s & 7) ^ (r & 7));
        int v = v0 + r;
        if (v < N_VOX)
            *(int4*)(h1b + (size_t)v * CCH + c * 8) = bufmem[r * 16 + s];
    }
    if (blockIdx.x == 0 && tid < 16)
        *(int4*)(h1b + (size_t)N_VOX * CCH + tid * 8) = make_int4(0, 0, 0, 0);
}

// ---------------------------------------------------------------------------
// Kernel 3: conv2 via MFMA + fused tail. T3-minimum pipeline:
// per k: B-frags(16, first) -> STAGE(k+1) via global_load_lds (8, per-lane
// gather source, linear LDS dest) -> ds_read+64 MFMA (B waits leave STAGE in
// flight) -> asm vmcnt(0) -> raw s_barrier. One barrier per offset; gather
// latency hides under the whole MFMA phase.
// ---------------------------------------------------------------------------
#define STAGE2(bufsel, kq) {                                               \
    _Pragma("unroll") for (int u = 0; u < 8; ++u) {                        \
        int q = u * 256 + tid;                                             \
        int r = q >> 4, s = q & 15;                                        \
        int c = (s & 8) | ((s & 7) ^ (r & 7));                             \
        int idx = idxAll[(kq) * 128 + r];                                  \
        gload_lds16((const char*)h1b + ((size_t)idx << 8) + (c << 4),      \
                    (void*)&Abuf[bufsel][q]);                              \
    }                                                                      \
}

__global__ __launch_bounds__(256, 2) void conv2_mfma(
    const unsigned short* __restrict__ h1b, const int* __restrict__ nidx,
    const unsigned short* __restrict__ W2f, const float* __restrict__ b2,
    const unsigned short* __restrict__ W3f, const float* __restrict__ b3,
    const float* __restrict__ W4, const float* __restrict__ b4,
    float* __restrict__ out) {
    __shared__ int4 Abuf[2][2048];       // 2 x 32 KB A-tiles
    __shared__ int idxAll[KOFF * 128];   // 13.5 KB; reused as Osum in tail

    int tid = threadIdx.x;
    int l = tid & 63, w = tid >> 6;
    int mw = w >> 1, nwv = w & 1;
    int wg = xcd_swz(blockIdx.x, gridDim.x);
    int v0 = wg * 128;

    for (int g = tid; g < KOFF * 128; g += 256) {
        int k = g >> 7, vi = g & 127;
        int v = v0 + vi;
        idxAll[k * 128 + vi] = (v < N_VOX) ? nidx[(size_t)k * N_VOX + v] : N_VOX;
    }
    __syncthreads();

    f32x4 acc[4][4];
#pragma unroll
    for (int m = 0; m < 4; ++m)
#pragma unroll
        for (int n = 0; n < 4; ++n) acc[m][n] = (f32x4)0.f;

    // prologue: stage tile k=0
    STAGE2(0, 0);
    asm volatile("s_waitcnt vmcnt(0)" ::: "memory");
    __builtin_amdgcn_s_barrier();

    for (int k = 0; k < KOFF; ++k) {
        int cur = k & 1;
        const unsigned short* wb = W2f + (size_t)k * 16384;
        // 1) all 16 B-frag loads FIRST (their waits then resolve at
        //    vmcnt(8), leaving the 8 staging loads in flight)
        bf16x8 bf[4][4];
#pragma unroll
        for (int kk = 0; kk < 4; ++kk)
#pragma unroll
            for (int n = 0; n < 4; ++n)
                bf[kk][n] = *(const bf16x8*)(wb +
                    ((size_t)(kk * 8 + nwv * 4 + n) * 64 + l) * 8);
        __builtin_amdgcn_sched_barrier(0);
        // 2) issue next tile's gather straight to LDS
        if (k + 1 < KOFF) { STAGE2(cur ^ 1, k + 1); }
        __builtin_amdgcn_sched_barrier(0);
        // 3) compute tile k from LDS
#pragma unroll
        for (int kk = 0; kk < 4; ++kk) {
            bf16x8 a[4];
#pragma unroll
            for (int m = 0; m < 4; ++m) {
                int r = mw * 64 + m * 16 + (l & 15);
                int c = kk * 4 + (l >> 4);
                int s = (c & 8) | ((c & 7) ^ (r & 7));
                a[m] = *(const bf16x8*)&Abuf[cur][r * 16 + s];
            }
#pragma unroll
            for (int m = 0; m < 4; ++m)
#pragma unroll
                for (int n = 0; n < 4; ++n)
                    acc[m][n] = __builtin_amdgcn_mfma_f32_16x16x32_bf16(
                        a[m], bf[kk][n], acc[m][n], 0, 0, 0);
        }
        // 4) confirm own staging writes, then barrier (all waves ditto)
        asm volatile("s_waitcnt vmcnt(0)" ::: "memory");
        __builtin_amdgcn_s_barrier();
    }

    // ---- fused tail: H = bf16(silu(acc+b2)) -> LDS; P = H @ W3; out ----
    float bias2[4];
#pragma unroll
    for (int n = 0; n < 4; ++n) bias2[n] = b2[nwv * 64 + n * 16 + (l & 15)];
    unsigned short* H16 = (unsigned short*)&Abuf[0][0];
#pragma unroll
    for (int m = 0; m < 4; ++m) {
        int rbase = mw * 64 + m * 16 + (l >> 4) * 4;
#pragma unroll
        for (int n = 0; n < 4; ++n) {
            int ch = nwv * 64 + n * 16 + (l & 15);
            int c = ch >> 3;
            f32x4 d = acc[m][n];
#pragma unroll
            for (int ri = 0; ri < 4; ++ri) {
                int r = rbase + ri;
                int s = (c & 8) | ((c & 7) ^ (r & 7));
                H16[r * 128 + s * 8 + (ch & 7)] = f2bf(silu_f(d[ri] + bias2[n]));
            }
        }
    }
    __syncthreads();

    f32x4 p[4][4];
#pragma unroll
    for (int m = 0; m < 4; ++m)
#pragma unroll
        for (int n = 0; n < 4; ++n) p[m][n] = (f32x4)0.f;
#pragma unroll
    for (int kk = 0; kk < 4; ++kk) {
        bf16x8 a[4], b[4];
#pragma unroll
        for (int n = 0; n < 4; ++n) {
            int nf = nwv * 4 + n;
            b[n] = *(const bf16x8*)(W3f + ((size_t)(kk * 8 + nf) * 64 + l) * 8);
        }
#pragma unroll
        for (int m = 0; m < 4; ++m) {
            int r = mw * 64 + m * 16 + (l & 15);
            int c = kk * 4 + (l >> 4);
            int s = (c & 8) | ((c & 7) ^ (r & 7));
            a[m] = *(const bf16x8*)&H16[r * 128 + s * 8];
        }
#pragma unroll
        for (int m = 0; m < 4; ++m)
#pragma unroll
            for (int n = 0; n < 4; ++n)
                p[m][n] = __builtin_amdgcn_mfma_f32_16x16x32_bf16(
                    a[m], b[n], p[m][n], 0, 0, 0);
    }

    float w4v[4], b3v[4];
#pragma unroll
    for (int n = 0; n < 4; ++n) {
        int ch = nwv * 64 + n * 16 + (l & 15);
        w4v[n] = W4[ch];
        b3v[n] = b3[ch];
    }
    float* Osum = (float*)idxAll;
#pragma unroll
    for (int m = 0; m < 4; ++m) {
        float po[4] = {0.f, 0.f, 0.f, 0.f};
#pragma unroll
        for (int n = 0; n < 4; ++n) {
            f32x4 d = p[m][n];
#pragma unroll
            for (int ri = 0; ri < 4; ++ri)
                po[ri] += silu_f(d[ri] + b3v[n]) * w4v[n];
        }
#pragma unroll
        for (int off = 1; off < 16; off <<= 1)
#pragma unroll
            for (int ri = 0; ri < 4; ++ri)
                po[ri] += __shfl_xor(po[ri], off, 64);
        if ((l & 15) == 0) {
            int rbase = mw * 64 + m * 16 + (l >> 4) * 4;
#pragma unroll
            for (int ri = 0; ri < 4; ++ri)
                Osum[nwv * 128 + rbase + ri] = po[ri];
        }
    }
    __syncthreads();
    if (tid < 128) {
        int v = v0 + tid;
        if (v < N_VOX) out[v] = Osum[tid] + Osum[128 + tid] + b4[0];
    }
}

// ---------------------------------------------------------------------------
extern "C" void kernel_launch(void* const* d_in, const int* in_sizes, int n_in,
                              void* d_out, int out_size, void* d_ws,
                              size_t ws_size, hipStream_t stream) {
    const float* feat = (const float*)d_in[0];
    const int* t      = (const int*)d_in[1];
    const int* nidx   = (const int*)d_in[2];
    const float* W1   = (const float*)d_in[3];
    const float* b1   = (const float*)d_in[4];
    const float* W2   = (const float*)d_in[5];
    const float* b2   = (const float*)d_in[6];
    const float* W3   = (const float*)d_in[7];
    const float* b3   = (const float*)d_in[8];
    const float* W4   = (const float*)d_in[9];
    const float* b4   = (const float*)d_in[10];
    float* out = (float*)d_out;

    char* ws = (char*)d_ws;
    size_t off = 0;
    unsigned short* xeb = (unsigned short*)(ws + off);
    off += ((size_t)(N_VOX + 1) * 8 * 2 + 255) & ~(size_t)255;
    unsigned short* h1b = (unsigned short*)(ws + off);
    off += ((size_t)(N_VOX + 1) * CCH * 2 + 255) & ~(size_t)255;
    unsigned short* W1f = (unsigned short*)(ws + off);
    off += ((size_t)7 * 8 * 64 * 8 * 2 + 255) & ~(size_t)255;
    unsigned short* W2f = (unsigned short*)(ws + off);
    off += ((size_t)KOFF * 4 * 8 * 64 * 8 * 2 + 255) & ~(size_t)255;
    unsigned short* W3f = (unsigned short*)(ws + off);

    int grid1 = (N_VOX + 127) / 128;
    int grid2 = (N_VOX + 127) / 128;
    embed_kernel<<<(N_VOX + 1 + 255) / 256, 256, 0, stream>>>(feat, t, xeb);
    convert_w1<<<(7 * 8 * 64 + 255) / 256, 256, 0, stream>>>(W1, W1f);
    convert_w2<<<(KOFF * 4 * 8 * 64) / 256, 256, 0, stream>>>(W2, W2f);
    convert_w3<<<(4 * 8 * 64 + 255) / 256, 256, 0, stream>>>(W3, W3f);
    conv1_mfma<<<grid1, 256, 0, stream>>>(xeb, nidx, W1f, b1, h1b);
    conv2_mfma<<<grid2, 256, 0, stream>>>(h1b, nidx, W2f, b2, W3f, b3, W4, b4, out);
}